// Round 1
// baseline (142.059 us; speedup 1.0000x reference)
//
#include <hip/hip_runtime.h>

// TMoELayer: B=4,T=4096 -> N=16384 tokens, D_IN=1024, D_OUT=1024, E=8, TOP_K=2, R=16
// out = 2.0 * einsum(btr,bte,eor->bto) with gate = scatter(softmax(top2(x@w_route^T)))
constexpr float SCALING = 2.0f;  // alpha/r = 32/16

__device__ __forceinline__ float dot4f(float4 a, float4 b){
  return fmaf(a.x, b.x, fmaf(a.y, b.y, fmaf(a.z, b.z, a.w * b.w)));
}

// ---------------- Kernel 1: router logits + top2 softmax + ce = 2*x@compress^T
// block = 1024 threads (16 waves), wave-per-token. Weights (24 rows x 1024) staged
// in LDS in two 48KB phases. x row lives in 16 VGPRs/lane.
__global__ __launch_bounds__(1024) void k1_route(
    const float* __restrict__ x, const float* __restrict__ w_route,
    const float* __restrict__ compress, float* __restrict__ ce_ws,
    float4* __restrict__ gate_ws, int ntok)
{
  __shared__ float wl[12 * 1024];  // 48 KB, reused across 2 phases
  const int tid   = threadIdx.x;
  const int lane  = tid & 63;
  const int wv    = tid >> 6;
  const int token = blockIdx.x * 16 + wv;
  const bool valid = token < ntok;

  float4 xv[4];
  if (valid){
    const float4* xr = (const float4*)(x + (size_t)token * 1024);
    #pragma unroll
    for (int c = 0; c < 4; ++c) xv[c] = xr[lane + 64 * c];
  } else {
    #pragma unroll
    for (int c = 0; c < 4; ++c) xv[c] = make_float4(0.f, 0.f, 0.f, 0.f);
  }

  float acc[24];  // 0..7 logits, 8..23 ce
  #pragma unroll
  for (int ph = 0; ph < 2; ++ph){
    __syncthreads();  // protect previous-phase LDS reads
    #pragma unroll
    for (int i = 0; i < 3; ++i){
      int flat = tid + i * 1024;       // float4 index in [0,3072)
      int row  = flat >> 8;            // 0..11
      int col4 = flat & 255;
      int g = ph * 12 + row;           // global weight row 0..23
      const float* src = (g < 8) ? (w_route + g * 1024) : (compress + (g - 8) * 1024);
      ((float4*)wl)[flat] = ((const float4*)src)[col4];
    }
    __syncthreads();
    #pragma unroll
    for (int jl = 0; jl < 12; ++jl){
      const float4* wr = (const float4*)(wl + jl * 1024);
      float s = dot4f(xv[0], wr[lane])       + dot4f(xv[1], wr[lane + 64])
              + dot4f(xv[2], wr[lane + 128]) + dot4f(xv[3], wr[lane + 192]);
      acc[ph * 12 + jl] = s;
    }
  }

  // butterfly reduce all 24 partial dots across the wave (result in every lane)
  #pragma unroll
  for (int m = 1; m < 64; m <<= 1){
    #pragma unroll
    for (int j = 0; j < 24; ++j) acc[j] += __shfl_xor(acc[j], m, 64);
  }

  if (valid && lane == 0){
    // top-2 over logits acc[0..7]; ties -> lower index first (matches jax top_k)
    float v0 = acc[0]; int e0 = 0;
    #pragma unroll
    for (int e = 1; e < 8; ++e) if (acc[e] > v0){ v0 = acc[e]; e0 = e; }
    float v1 = -3.402823466e38f; int e1 = 0;
    #pragma unroll
    for (int e = 0; e < 8; ++e) if (e != e0 && acc[e] > v1){ v1 = acc[e]; e1 = e; }
    float ex  = __expf(v1 - v0);       // <= 1
    float inv = 1.0f / (1.0f + ex);
    float w0 = inv, w1 = ex * inv;
    gate_ws[token] = make_float4(__int_as_float(e0), __int_as_float(e1), w0, w1);
    float4* cw = (float4*)(ce_ws + (size_t)token * 16);
    cw[0] = make_float4(SCALING*acc[ 8], SCALING*acc[ 9], SCALING*acc[10], SCALING*acc[11]);
    cw[1] = make_float4(SCALING*acc[12], SCALING*acc[13], SCALING*acc[14], SCALING*acc[15]);
    cw[2] = make_float4(SCALING*acc[16], SCALING*acc[17], SCALING*acc[18], SCALING*acc[19]);
    cw[3] = make_float4(SCALING*acc[20], SCALING*acc[21], SCALING*acc[22], SCALING*acc[23]);
  }
}

// ---------------- Kernel 2: gate-weighted expert combine
// thread <-> output column o; routed[e][o][0..15] for ALL 8 experts held in
// 128 VGPRs; expert picked via readfirstlane + uniform switch (keeps register
// arrays statically indexed). 64 tokens per block, ce/gate staged in LDS.
__device__ __forceinline__ float dot16f(const float* ce, const float* row){
  float s = 0.f;
  #pragma unroll
  for (int r = 0; r < 16; ++r) s = fmaf(ce[r], row[r], s);
  return s;
}

__global__ __launch_bounds__(256) void k2_combine(
    const float* __restrict__ routed, const float* __restrict__ ce_ws,
    const float4* __restrict__ gate_ws, float* __restrict__ out, int ntok)
{
  const int tid    = threadIdx.x;
  const int ochunk = blockIdx.x & 3;
  const int tchunk = blockIdx.x >> 2;
  const int o      = ochunk * 256 + tid;
  const int token0 = tchunk * 64;

  float rt[8][16];
  #pragma unroll
  for (int e = 0; e < 8; ++e){
    const float4* rp = (const float4*)(routed + ((size_t)e * 1024 + o) * 16);
    #pragma unroll
    for (int q = 0; q < 4; ++q){
      float4 v = rp[q];
      rt[e][q*4+0] = v.x; rt[e][q*4+1] = v.y; rt[e][q*4+2] = v.z; rt[e][q*4+3] = v.w;
    }
  }

  __shared__ float  ce_s[64 * 16];
  __shared__ float4 gate_s[64];
  ((float4*)ce_s)[tid] = ((const float4*)(ce_ws + (size_t)token0 * 16))[tid];
  if (tid < 64) gate_s[tid] = gate_ws[token0 + tid];
  __syncthreads();

  #pragma unroll 1
  for (int t = 0; t < 64; ++t){
    float4 g = gate_s[t];
    int e0 = __builtin_amdgcn_readfirstlane(__float_as_int(g.x));
    int e1 = __builtin_amdgcn_readfirstlane(__float_as_int(g.y));
    float w0 = g.z, w1 = g.w;
    float ce[16];
    const float4* cp = (const float4*)(ce_s + t * 16);
    #pragma unroll
    for (int q = 0; q < 4; ++q){
      float4 v = cp[q];
      ce[q*4+0] = v.x; ce[q*4+1] = v.y; ce[q*4+2] = v.z; ce[q*4+3] = v.w;
    }
    float d0, d1;
    switch (e0){
      case 0: d0 = dot16f(ce, rt[0]); break;
      case 1: d0 = dot16f(ce, rt[1]); break;
      case 2: d0 = dot16f(ce, rt[2]); break;
      case 3: d0 = dot16f(ce, rt[3]); break;
      case 4: d0 = dot16f(ce, rt[4]); break;
      case 5: d0 = dot16f(ce, rt[5]); break;
      case 6: d0 = dot16f(ce, rt[6]); break;
      default: d0 = dot16f(ce, rt[7]); break;
    }
    switch (e1){
      case 0: d1 = dot16f(ce, rt[0]); break;
      case 1: d1 = dot16f(ce, rt[1]); break;
      case 2: d1 = dot16f(ce, rt[2]); break;
      case 3: d1 = dot16f(ce, rt[3]); break;
      case 4: d1 = dot16f(ce, rt[4]); break;
      case 5: d1 = dot16f(ce, rt[5]); break;
      case 6: d1 = dot16f(ce, rt[6]); break;
      default: d1 = dot16f(ce, rt[7]); break;
    }
    out[(size_t)(token0 + t) * 1024 + o] = fmaf(w0, d0, w1 * d1);
  }
}

extern "C" void kernel_launch(void* const* d_in, const int* in_sizes, int n_in,
                              void* d_out, int out_size, void* d_ws, size_t ws_size,
                              hipStream_t stream)
{
  const float* x        = (const float*)d_in[0];
  const float* w_route  = (const float*)d_in[1];
  const float* compress = (const float*)d_in[2];
  const float* routed   = (const float*)d_in[3];
  float* out = (float*)d_out;

  const int ntok = in_sizes[0] / 1024;   // 16384 (B*T)
  float*  ce_ws   = (float*)d_ws;                                     // ntok*16 f32 (1 MB)
  float4* gate_ws = (float4*)((char*)d_ws + (size_t)ntok * 16 * 4);   // ntok float4 (256 KB)

  const int blocks1 = (ntok + 15) / 16;
  k1_route<<<blocks1, 1024, 0, stream>>>(x, w_route, compress, ce_ws, gate_ws, ntok);

  const int blocks2 = (ntok / 64) * 4;   // 4 o-chunks x 256 token-chunks
  k2_combine<<<blocks2, 256, 0, stream>>>(routed, ce_ws, gate_ws, out, ntok);
}

// Round 2
// 97.824 us; speedup vs baseline: 1.4522x; 1.4522x over previous
//
#include <hip/hip_runtime.h>

// TMoELayer: B=4,T=4096 -> N=16384 tokens, D_IN=1024, D_OUT=1024, E=8, TOP_K=2, R=16
// out = 2.0 * einsum(btr,bte,eor->bto), gate = scatter(softmax(top2(x@w_route^T)))
constexpr float SCALING = 2.0f;  // alpha/r = 32/16

__device__ __forceinline__ void load_lds16(const float* g, float* l){
  __builtin_amdgcn_global_load_lds(
      (const __attribute__((address_space(1))) void*)g,
      (__attribute__((address_space(3))) void*)l, 16, 0, 0);
}

// ---------------- Kernel 1: logits + top2 softmax + ce = 2*x@compress^T
// 256 thr = 4 waves; wave handles 4 tokens (full 1024 dims, 16 floats/lane/token).
// 24 weight rows processed in 2 LDS phases of 12 rows (48KB), staged via
// global_load_lds. Reduction: fold 4 tokens onto lane bits 0-1, then butterfly.
// Assumes ntok % 16 == 0 (harness: ntok = 16384).
__global__ __launch_bounds__(256, 2) void k1_route(
    const float* __restrict__ x, const float* __restrict__ w_route,
    const float* __restrict__ compress, float* __restrict__ ce_ws,
    float4* __restrict__ gate_ws, int ntok)
{
  __shared__ float wl[12 * 1024];  // 48 KB
  const int tid  = threadIdx.x;
  const int lane = tid & 63;
  const int wv   = tid >> 6;
  const int tok0 = blockIdx.x * 16 + wv * 4;
  const int b0 = lane & 1, b1 = lane & 2;

  // x fragments: 4 tokens x 4 float4 per lane (64 VGPRs), loaded once
  float4 xv[4][4];
  const float4* xr = (const float4*)(x + (size_t)tok0 * 1024);
  #pragma unroll
  for (int t = 0; t < 4; ++t)
    #pragma unroll
    for (int c = 0; c < 4; ++c)
      xv[t][c] = xr[t * 256 + c * 64 + lane];

  float acc[4][12];
  float r[12];

  // ---- stage phase 0 rows (w_route 0..7, compress 0..3)
  #pragma unroll
  for (int i = 0; i < 12; ++i){
    const float* src = (i < 8) ? (w_route + (size_t)i * 1024)
                               : (compress + (size_t)(i - 8) * 1024);
    load_lds16(src + wv * 256 + lane * 4, &wl[i * 1024 + wv * 256]);
  }
  __syncthreads();  // vmcnt(0) drained by compiler before barrier

  // ---- compute phase 0
  #pragma unroll
  for (int t = 0; t < 4; ++t)
    #pragma unroll
    for (int j = 0; j < 12; ++j) acc[t][j] = 0.f;
  #pragma unroll
  for (int j = 0; j < 12; ++j){
    const float4* wr = (const float4*)(wl + j * 1024);
    #pragma unroll
    for (int c = 0; c < 4; ++c){
      float4 w4 = wr[c * 64 + lane];
      #pragma unroll
      for (int t = 0; t < 4; ++t)
        acc[t][j] = fmaf(xv[t][c].x, w4.x, fmaf(xv[t][c].y, w4.y,
                    fmaf(xv[t][c].z, w4.z, fmaf(xv[t][c].w, w4.w, acc[t][j]))));
    }
  }
  __syncthreads();  // all waves done reading wl phase 0

  // ---- issue phase-1 staging now; reduction below overlaps the load latency
  #pragma unroll
  for (int i = 0; i < 12; ++i){
    const float* src = compress + (size_t)(i + 4) * 1024;  // rows 12..23 = compress 4..15
    load_lds16(src + wv * 256 + lane * 4, &wl[i * 1024 + wv * 256]);
  }

  // ---- reduce phase 0: fold tokens onto lane bits 0-1, butterfly bits 2-5
  {
    float r01[12], r23[12];
    #pragma unroll
    for (int j = 0; j < 12; ++j){
      float a = acc[0][j], b = acc[1][j];
      r01[j] = (b0 ? b : a) + __shfl_xor(b0 ? a : b, 1, 64);
      float c2 = acc[2][j], d = acc[3][j];
      r23[j] = (b0 ? d : c2) + __shfl_xor(b0 ? c2 : d, 1, 64);
    }
    #pragma unroll
    for (int j = 0; j < 12; ++j){
      float a = r01[j], b = r23[j];
      r[j] = (b1 ? b : a) + __shfl_xor(b1 ? a : b, 2, 64);
    }
    #pragma unroll
    for (int m = 4; m < 64; m <<= 1)
      #pragma unroll
      for (int j = 0; j < 12; ++j) r[j] += __shfl_xor(r[j], m, 64);
  }
  // lane l (l<4) now holds token tok0+l: logits r[0..7], ce[0..3] = r[8..11]
  if (lane < 4 && tok0 + lane < ntok){
    const int token = tok0 + lane;
    float v0 = r[0]; int e0 = 0;
    #pragma unroll
    for (int e = 1; e < 8; ++e) if (r[e] > v0){ v0 = r[e]; e0 = e; }
    float v1 = -3.402823466e38f; int e1 = 0;
    #pragma unroll
    for (int e = 0; e < 8; ++e) if (e != e0 && r[e] > v1){ v1 = r[e]; e1 = e; }
    float ex  = __expf(v1 - v0);
    float inv = 1.0f / (1.0f + ex);
    gate_ws[token] = make_float4(__int_as_float(e0), __int_as_float(e1), inv, ex * inv);
    ((float4*)(ce_ws + (size_t)token * 16))[0] =
        make_float4(SCALING*r[8], SCALING*r[9], SCALING*r[10], SCALING*r[11]);
  }
  __syncthreads();  // phase-1 staging complete

  // ---- compute phase 1 (compress rows 4..15)
  #pragma unroll
  for (int t = 0; t < 4; ++t)
    #pragma unroll
    for (int j = 0; j < 12; ++j) acc[t][j] = 0.f;
  #pragma unroll
  for (int j = 0; j < 12; ++j){
    const float4* wr = (const float4*)(wl + j * 1024);
    #pragma unroll
    for (int c = 0; c < 4; ++c){
      float4 w4 = wr[c * 64 + lane];
      #pragma unroll
      for (int t = 0; t < 4; ++t)
        acc[t][j] = fmaf(xv[t][c].x, w4.x, fmaf(xv[t][c].y, w4.y,
                    fmaf(xv[t][c].z, w4.z, fmaf(xv[t][c].w, w4.w, acc[t][j]))));
    }
  }
  {
    float r01[12], r23[12];
    #pragma unroll
    for (int j = 0; j < 12; ++j){
      float a = acc[0][j], b = acc[1][j];
      r01[j] = (b0 ? b : a) + __shfl_xor(b0 ? a : b, 1, 64);
      float c2 = acc[2][j], d = acc[3][j];
      r23[j] = (b0 ? d : c2) + __shfl_xor(b0 ? c2 : d, 1, 64);
    }
    #pragma unroll
    for (int j = 0; j < 12; ++j){
      float a = r01[j], b = r23[j];
      r[j] = (b1 ? b : a) + __shfl_xor(b1 ? a : b, 2, 64);
    }
    #pragma unroll
    for (int m = 4; m < 64; m <<= 1)
      #pragma unroll
      for (int j = 0; j < 12; ++j) r[j] += __shfl_xor(r[j], m, 64);
  }
  if (lane < 4 && tok0 + lane < ntok){
    float4* cw = (float4*)(ce_ws + (size_t)(tok0 + lane) * 16);
    cw[1] = make_float4(SCALING*r[0], SCALING*r[1], SCALING*r[ 2], SCALING*r[ 3]);
    cw[2] = make_float4(SCALING*r[4], SCALING*r[5], SCALING*r[ 6], SCALING*r[ 7]);
    cw[3] = make_float4(SCALING*r[8], SCALING*r[9], SCALING*r[10], SCALING*r[11]);
  }
}

// ---------------- Kernel 2: gate-weighted expert combine
__device__ __forceinline__ float dot16f(const float* ce, const float* row){
  // 4-way split accumulation: ~26 cyc latency vs 64 for a serial chain
  float s0 = 0.f, s1 = 0.f, s2 = 0.f, s3 = 0.f;
  #pragma unroll
  for (int r = 0; r < 4; ++r){
    s0 = fmaf(ce[r],      row[r],      s0);
    s1 = fmaf(ce[r + 4],  row[r + 4],  s1);
    s2 = fmaf(ce[r + 8],  row[r + 8],  s2);
    s3 = fmaf(ce[r + 12], row[r + 12], s3);
  }
  return (s0 + s1) + (s2 + s3);
}

__global__ __launch_bounds__(256, 2) void k2_combine(
    const float* __restrict__ routed, const float* __restrict__ ce_ws,
    const float4* __restrict__ gate_ws, float* __restrict__ out, int ntok)
{
  const int tid    = threadIdx.x;
  const int ochunk = blockIdx.x & 3;
  const int tchunk = blockIdx.x >> 2;
  const int o      = ochunk * 256 + tid;
  const int token0 = tchunk * 64;

  float rt[8][16];  // routed[e][o][*] for all experts: 128 VGPRs
  #pragma unroll
  for (int e = 0; e < 8; ++e){
    const float4* rp = (const float4*)(routed + ((size_t)e * 1024 + o) * 16);
    #pragma unroll
    for (int q = 0; q < 4; ++q){
      float4 v = rp[q];
      rt[e][q*4+0] = v.x; rt[e][q*4+1] = v.y; rt[e][q*4+2] = v.z; rt[e][q*4+3] = v.w;
    }
  }

  __shared__ float  ce_s[64 * 16];
  __shared__ float4 gate_s[64];
  ((float4*)ce_s)[tid] = ((const float4*)(ce_ws + (size_t)token0 * 16))[tid];
  if (tid < 64) gate_s[tid] = gate_ws[token0 + tid];
  __syncthreads();

  #pragma unroll 2
  for (int t = 0; t < 64; ++t){
    float4 g = gate_s[t];
    int e0 = __builtin_amdgcn_readfirstlane(__float_as_int(g.x));
    int e1 = __builtin_amdgcn_readfirstlane(__float_as_int(g.y));
    float w0 = g.z, w1 = g.w;
    float ce[16];
    const float4* cp = (const float4*)(ce_s + t * 16);
    #pragma unroll
    for (int q = 0; q < 4; ++q){
      float4 v = cp[q];
      ce[q*4+0] = v.x; ce[q*4+1] = v.y; ce[q*4+2] = v.z; ce[q*4+3] = v.w;
    }
    float d0, d1;
    switch (e0){
      case 0: d0 = dot16f(ce, rt[0]); break;
      case 1: d0 = dot16f(ce, rt[1]); break;
      case 2: d0 = dot16f(ce, rt[2]); break;
      case 3: d0 = dot16f(ce, rt[3]); break;
      case 4: d0 = dot16f(ce, rt[4]); break;
      case 5: d0 = dot16f(ce, rt[5]); break;
      case 6: d0 = dot16f(ce, rt[6]); break;
      default: d0 = dot16f(ce, rt[7]); break;
    }
    switch (e1){
      case 0: d1 = dot16f(ce, rt[0]); break;
      case 1: d1 = dot16f(ce, rt[1]); break;
      case 2: d1 = dot16f(ce, rt[2]); break;
      case 3: d1 = dot16f(ce, rt[3]); break;
      case 4: d1 = dot16f(ce, rt[4]); break;
      case 5: d1 = dot16f(ce, rt[5]); break;
      case 6: d1 = dot16f(ce, rt[6]); break;
      default: d1 = dot16f(ce, rt[7]); break;
    }
    out[(size_t)(token0 + t) * 1024 + o] = fmaf(w0, d0, w1 * d1);
  }
}

extern "C" void kernel_launch(void* const* d_in, const int* in_sizes, int n_in,
                              void* d_out, int out_size, void* d_ws, size_t ws_size,
                              hipStream_t stream)
{
  const float* x        = (const float*)d_in[0];
  const float* w_route  = (const float*)d_in[1];
  const float* compress = (const float*)d_in[2];
  const float* routed   = (const float*)d_in[3];
  float* out = (float*)d_out;

  const int ntok = in_sizes[0] / 1024;   // 16384 (B*T)
  float*  ce_ws   = (float*)d_ws;                                     // ntok*16 f32 (1 MB)
  float4* gate_ws = (float4*)((char*)d_ws + (size_t)ntok * 16 * 4);   // ntok float4 (256 KB)

  const int blocks1 = ntok / 16;         // 16 tokens per block (4 per wave)
  k1_route<<<blocks1, 256, 0, stream>>>(x, w_route, compress, ce_ws, gate_ws, ntok);

  const int blocks2 = (ntok / 64) * 4;   // 4 o-chunks x 256 token-chunks
  k2_combine<<<blocks2, 256, 0, stream>>>(routed, ce_ws, gate_ws, out, ntok);
}

// Round 3
// 77.316 us; speedup vs baseline: 1.8374x; 1.2653x over previous
//
#include <hip/hip_runtime.h>

// TMoELayer: B=4,T=4096 -> N=16384 tokens, D_IN=1024, D_OUT=1024, E=8, TOP_K=2, R=16
// out[n][o] = sum_k Y[n][k] * Bt[o][k],  k = e*16+r
//   Y[n][e*16+r] = gate_w(n,e) * 2 * ce[n][r]   (only top-2 e nonzero)
//   Bt[o][e*16+r] = routed[e][o][r]
constexpr float SCALING = 2.0f;  // alpha/r = 32/16

typedef __attribute__((ext_vector_type(8))) _Float16 half8;
typedef __attribute__((ext_vector_type(4))) float    f32x4;

__device__ __forceinline__ void load_lds16(const float* g, float* l){
  __builtin_amdgcn_global_load_lds(
      (const __attribute__((address_space(1))) void*)g,
      (__attribute__((address_space(3))) void*)l, 16, 0, 0);
}

// ---------------- Kernel 0: Bt[o][k] = (f16)routed[e][o][r], k = e*16+r
// 8192 threads; thread t: e = t&7, o = t>>3. Writes fully coalesced (32B/thread).
__global__ __launch_bounds__(256) void k0_prep(
    const float* __restrict__ routed, _Float16* __restrict__ Bt)
{
  const int t = blockIdx.x * 256 + threadIdx.x;   // 0..8191
  const int e = t & 7, o = t >> 3;
  const float4* rp = (const float4*)(routed + ((size_t)e * 1024 + o) * 16);
  float4 a = rp[0], b = rp[1], c = rp[2], d = rp[3];
  half8 h0, h1;
  h0[0]=(_Float16)a.x; h0[1]=(_Float16)a.y; h0[2]=(_Float16)a.z; h0[3]=(_Float16)a.w;
  h0[4]=(_Float16)b.x; h0[5]=(_Float16)b.y; h0[6]=(_Float16)b.z; h0[7]=(_Float16)b.w;
  h1[0]=(_Float16)c.x; h1[1]=(_Float16)c.y; h1[2]=(_Float16)c.z; h1[3]=(_Float16)c.w;
  h1[4]=(_Float16)d.x; h1[5]=(_Float16)d.y; h1[6]=(_Float16)d.z; h1[7]=(_Float16)d.w;
  _Float16* dst = Bt + (size_t)o * 128 + e * 16;
  *(half8*)(dst)     = h0;
  *(half8*)(dst + 8) = h1;
}

// ---------------- Kernel 1: router + top2 softmax + ce, emits Y rows (f16)
// 256 thr = 4 waves; wave handles 4 tokens. 24 weight rows in 2 LDS phases of 12.
// Reduction: fold 4 tokens onto lane bits 0-1, butterfly bits 2-5 -> lane l holds
// token (l&3)'s full r[]. Y-write: lane l covers token l&3, chunk e = l>>3,
// half = (l>>2)&1 -> one 16B store per lane, all register indices compile-time.
__global__ __launch_bounds__(256, 2) void k1_route(
    const float* __restrict__ x, const float* __restrict__ w_route,
    const float* __restrict__ compress, _Float16* __restrict__ Y, int ntok)
{
  __shared__ float wl[12 * 1024];  // 48 KB
  const int tid  = threadIdx.x;
  const int lane = tid & 63;
  const int wv   = tid >> 6;
  const int tok0 = blockIdx.x * 16 + wv * 4;
  const int b0 = lane & 1, b1 = lane & 2;

  float4 xv[4][4];
  const float4* xr = (const float4*)(x + (size_t)tok0 * 1024);
  #pragma unroll
  for (int t = 0; t < 4; ++t)
    #pragma unroll
    for (int c = 0; c < 4; ++c)
      xv[t][c] = xr[t * 256 + c * 64 + lane];

  float acc[4][12];
  float r[12];
  float lg[8];    // logits, saved across phase 1
  float ce03[4];  // ce[0..3], saved across phase 1

  // ---- stage phase 0 (w_route 0..7, compress 0..3)
  #pragma unroll
  for (int i = 0; i < 12; ++i){
    const float* src = (i < 8) ? (w_route + (size_t)i * 1024)
                               : (compress + (size_t)(i - 8) * 1024);
    load_lds16(src + wv * 256 + lane * 4, &wl[i * 1024 + wv * 256]);
  }
  __syncthreads();

  #pragma unroll
  for (int t = 0; t < 4; ++t)
    #pragma unroll
    for (int j = 0; j < 12; ++j) acc[t][j] = 0.f;
  #pragma unroll
  for (int j = 0; j < 12; ++j){
    const float4* wr = (const float4*)(wl + j * 1024);
    #pragma unroll
    for (int c = 0; c < 4; ++c){
      float4 w4 = wr[c * 64 + lane];
      #pragma unroll
      for (int t = 0; t < 4; ++t)
        acc[t][j] = fmaf(xv[t][c].x, w4.x, fmaf(xv[t][c].y, w4.y,
                    fmaf(xv[t][c].z, w4.z, fmaf(xv[t][c].w, w4.w, acc[t][j]))));
    }
  }
  __syncthreads();  // all waves done reading phase-0 wl

  // ---- issue phase-1 staging (compress rows 4..15); reduction overlaps latency
  #pragma unroll
  for (int i = 0; i < 12; ++i){
    const float* src = compress + (size_t)(i + 4) * 1024;
    load_lds16(src + wv * 256 + lane * 4, &wl[i * 1024 + wv * 256]);
  }

  {
    float r01[12], r23[12];
    #pragma unroll
    for (int j = 0; j < 12; ++j){
      float a = acc[0][j], b = acc[1][j];
      r01[j] = (b0 ? b : a) + __shfl_xor(b0 ? a : b, 1, 64);
      float c2 = acc[2][j], d = acc[3][j];
      r23[j] = (b0 ? d : c2) + __shfl_xor(b0 ? c2 : d, 1, 64);
    }
    #pragma unroll
    for (int j = 0; j < 12; ++j){
      float a = r01[j], b = r23[j];
      r[j] = (b1 ? b : a) + __shfl_xor(b1 ? a : b, 2, 64);
    }
    #pragma unroll
    for (int m = 4; m < 64; m <<= 1)
      #pragma unroll
      for (int j = 0; j < 12; ++j) r[j] += __shfl_xor(r[j], m, 64);
  }
  #pragma unroll
  for (int j = 0; j < 8; ++j) lg[j] = r[j];
  #pragma unroll
  for (int j = 0; j < 4; ++j) ce03[j] = r[8 + j];
  __syncthreads();  // phase-1 staging complete

  // ---- compute phase 1 (compress rows 4..15)
  #pragma unroll
  for (int t = 0; t < 4; ++t)
    #pragma unroll
    for (int j = 0; j < 12; ++j) acc[t][j] = 0.f;
  #pragma unroll
  for (int j = 0; j < 12; ++j){
    const float4* wr = (const float4*)(wl + j * 1024);
    #pragma unroll
    for (int c = 0; c < 4; ++c){
      float4 w4 = wr[c * 64 + lane];
      #pragma unroll
      for (int t = 0; t < 4; ++t)
        acc[t][j] = fmaf(xv[t][c].x, w4.x, fmaf(xv[t][c].y, w4.y,
                    fmaf(xv[t][c].z, w4.z, fmaf(xv[t][c].w, w4.w, acc[t][j]))));
    }
  }
  {
    float r01[12], r23[12];
    #pragma unroll
    for (int j = 0; j < 12; ++j){
      float a = acc[0][j], b = acc[1][j];
      r01[j] = (b0 ? b : a) + __shfl_xor(b0 ? a : b, 1, 64);
      float c2 = acc[2][j], d = acc[3][j];
      r23[j] = (b0 ? d : c2) + __shfl_xor(b0 ? c2 : d, 1, 64);
    }
    #pragma unroll
    for (int j = 0; j < 12; ++j){
      float a = r01[j], b = r23[j];
      r[j] = (b1 ? b : a) + __shfl_xor(b1 ? a : b, 2, 64);
    }
    #pragma unroll
    for (int m = 4; m < 64; m <<= 1)
      #pragma unroll
      for (int j = 0; j < 12; ++j) r[j] += __shfl_xor(r[j], m, 64);
  }
  // lane l: token tok0+(l&3); ce[0..3]=ce03, ce[4..15]=r[0..11]

  const int token = tok0 + (lane & 3);
  if (token < ntok){
    // top-2 + softmax (computed redundantly in all 16 lanes of the token group)
    float v0 = lg[0]; int e0 = 0;
    #pragma unroll
    for (int e = 1; e < 8; ++e) if (lg[e] > v0){ v0 = lg[e]; e0 = e; }
    float v1 = -3.402823466e38f; int e1 = 0;
    #pragma unroll
    for (int e = 0; e < 8; ++e) if (e != e0 && lg[e] > v1){ v1 = lg[e]; e1 = e; }
    float ex  = __expf(v1 - v0);
    float inv = 1.0f / (1.0f + ex);
    float w0 = inv * SCALING, w1 = ex * inv * SCALING;

    const int chunk = lane >> 3;          // expert chunk 0..7
    const int hf    = (lane >> 2) & 1;    // which 8 of the 16 ce values
    float s = (chunk == e0) ? w0 : ((chunk == e1) ? w1 : 0.f);

    float cel[8] = { ce03[0], ce03[1], ce03[2], ce03[3], r[0], r[1], r[2], r[3] };
    float ceh[8] = { r[4], r[5], r[6], r[7], r[8], r[9], r[10], r[11] };
    half8 hv;
    #pragma unroll
    for (int j = 0; j < 8; ++j){
      float cj = hf ? ceh[j] : cel[j];
      hv[j] = (_Float16)(s * cj);
    }
    // byte offset: token*256 + (lane>>2)*16  -> 4 contiguous 256B rows per wave
    *(half8*)(Y + (size_t)token * 128 + (lane >> 2) * 8) = hv;
  }
}

// ---------------- Kernel 2: out = Y @ Bt^T via mfma_f32_16x16x32_f16
// block = 4 waves; wave computes 16 tokens x 64 cols (4 n-reps, 4 k-steps, 16 MFMA).
// XCD-swizzled grid: all 16 bn-blocks of one bm land on one XCD (A-tile L2 reuse).
__global__ __launch_bounds__(256) void k2_gemm(
    const _Float16* __restrict__ Y, const _Float16* __restrict__ Bt,
    float* __restrict__ out, int ntok)
{
  const int g   = blockIdx.x;
  const int xcd = g & 7;
  const int j   = g >> 3;
  const int bn  = j & 15;
  const int bm  = xcd * (gridDim.x >> 7) + (j >> 4);   // grid 4096 -> 32 bm per XCD
  const int lane = threadIdx.x & 63;
  const int wv   = threadIdx.x >> 6;
  const int n0   = bm * 64 + wv * 16;
  const int o0   = bn * 64;
  const int c15  = lane & 15;      // A-row / B-col / D-col
  const int kg   = lane >> 4;      // k-group 0..3

  const half8* Ap = (const half8*)(Y + (size_t)(n0 + c15) * 128) + kg;
  f32x4 acc[4] = {{0.f,0.f,0.f,0.f},{0.f,0.f,0.f,0.f},{0.f,0.f,0.f,0.f},{0.f,0.f,0.f,0.f}};

  #pragma unroll
  for (int s = 0; s < 4; ++s){
    half8 a = Ap[s * 4];
    #pragma unroll
    for (int nc = 0; nc < 4; ++nc){
      const half8* Bp = (const half8*)(Bt + (size_t)(o0 + nc * 16 + c15) * 128) + kg;
      half8 b = Bp[s * 4];
      acc[nc] = __builtin_amdgcn_mfma_f32_16x16x32_f16(a, b, acc[nc], 0, 0, 0);
    }
  }

  #pragma unroll
  for (int nc = 0; nc < 4; ++nc)
    #pragma unroll
    for (int v = 0; v < 4; ++v)
      out[(size_t)(n0 + kg * 4 + v) * 1024 + o0 + nc * 16 + c15] = acc[nc][v];
}

extern "C" void kernel_launch(void* const* d_in, const int* in_sizes, int n_in,
                              void* d_out, int out_size, void* d_ws, size_t ws_size,
                              hipStream_t stream)
{
  const float* x        = (const float*)d_in[0];
  const float* w_route  = (const float*)d_in[1];
  const float* compress = (const float*)d_in[2];
  const float* routed   = (const float*)d_in[3];
  float* out = (float*)d_out;

  const int ntok = in_sizes[0] / 1024;   // 16384 (B*T)
  _Float16* Yws = (_Float16*)d_ws;                                   // ntok*128 f16 (4 MB)
  _Float16* Bt  = (_Float16*)((char*)d_ws + (size_t)ntok * 128 * 2); // 1024*128 f16 (256 KB)

  k0_prep<<<32, 256, 0, stream>>>(routed, Bt);
  k1_route<<<ntok / 16, 256, 0, stream>>>(x, w_route, compress, Yws, ntok);
  k2_gemm<<<(ntok / 64) * 16, 256, 0, stream>>>(Yws, Bt, out, ntok);
}

// Round 4
// 69.805 us; speedup vs baseline: 2.0351x; 1.1076x over previous
//
#include <hip/hip_runtime.h>

// TMoELayer: B=4,T=4096 -> N=16384 tokens, D_IN=1024, D_OUT=1024, E=8, TOP_K=2, R=16
// out[n][o] = sum_k Yg[n][k] * Bt[o][k], k = e*16+r
//   Yg[n][e*16+r] = gate_w(n,e) * ce16[n][r],  ce16 = 2 * x @ compress^T (f16)
//   Bt[o][e*16+r] = routed[e][o][r] (f16)
constexpr float SCALING = 2.0f;  // alpha/r = 32/16

typedef __attribute__((ext_vector_type(8))) _Float16 half8;
typedef __attribute__((ext_vector_type(4))) _Float16 half4;
typedef __attribute__((ext_vector_type(4))) float    f32x4;

__device__ __forceinline__ float dot4f(float4 a, float4 b){
  return fmaf(a.x, b.x, fmaf(a.y, b.y, fmaf(a.z, b.z, a.w * b.w)));
}

__device__ __forceinline__ void load_lds16(const float* g, float* l){
  __builtin_amdgcn_global_load_lds(
      (const __attribute__((address_space(1))) void*)g,
      (__attribute__((address_space(3))) void*)l, 16, 0, 0);
}

// ---------------- Kernel 0: prep Bt[o][k]=(f16)routed[e][o][r]; Cf16 = (f16)(2*compress)
__global__ __launch_bounds__(256) void k0_prep(
    const float* __restrict__ routed, const float* __restrict__ compress,
    _Float16* __restrict__ Bt, _Float16* __restrict__ Cf16)
{
  const int bid = blockIdx.x, tid = threadIdx.x;
  if (bid < 32){
    const int t = bid * 256 + tid;            // 0..8191
    const int e = t & 7, o = t >> 3;
    const float4* rp = (const float4*)(routed + ((size_t)e * 1024 + o) * 16);
    float4 a = rp[0], b = rp[1], c = rp[2], d = rp[3];
    half8 h0, h1;
    h0[0]=(_Float16)a.x; h0[1]=(_Float16)a.y; h0[2]=(_Float16)a.z; h0[3]=(_Float16)a.w;
    h0[4]=(_Float16)b.x; h0[5]=(_Float16)b.y; h0[6]=(_Float16)b.z; h0[7]=(_Float16)b.w;
    h1[0]=(_Float16)c.x; h1[1]=(_Float16)c.y; h1[2]=(_Float16)c.z; h1[3]=(_Float16)c.w;
    h1[4]=(_Float16)d.x; h1[5]=(_Float16)d.y; h1[6]=(_Float16)d.z; h1[7]=(_Float16)d.w;
    _Float16* dst = Bt + (size_t)o * 128 + e * 16;
    *(half8*)(dst)     = h0;
    *(half8*)(dst + 8) = h1;
  } else {
    const int t2 = (bid - 32) * 256 + tid;    // 0..2047 (16*1024/8)
    const float4* cp = (const float4*)(compress) + (size_t)t2 * 2;
    float4 a = cp[0], b = cp[1];
    half8 h;
    h[0]=(_Float16)(SCALING*a.x); h[1]=(_Float16)(SCALING*a.y);
    h[2]=(_Float16)(SCALING*a.z); h[3]=(_Float16)(SCALING*a.w);
    h[4]=(_Float16)(SCALING*b.x); h[5]=(_Float16)(SCALING*b.y);
    h[6]=(_Float16)(SCALING*b.z); h[7]=(_Float16)(SCALING*b.w);
    *(half8*)(Cf16 + (size_t)t2 * 8) = h;
  }
}

// ---------------- Kernel 1: fused ce-MFMA + f32 router. Block = 16 tokens, 4 waves.
// ce: D[r][tok] = Cf16 (A, rows=r) x xf16 (B, cols=tok); each wave does a K-quarter,
// partials reduced through 4KB LDS. Router: f32 dots vs LDS-staged w_route; 2-token
// fold + butterfly; x re-read from L2 (block's tile just fetched by ce phase).
__global__ __launch_bounds__(256) void k_main(
    const float* __restrict__ x, const float* __restrict__ w_route,
    const _Float16* __restrict__ Cf16, _Float16* __restrict__ ce16,
    float4* __restrict__ gate_ws, int ntok)
{
  __shared__ float wlds[8 * 1024];   // 32 KB: w_route f32
  __shared__ f32x4 ceacc[4][64];     // 4 KB: per-wave ce partials
  const int tid = threadIdx.x, lane = tid & 63, wv = tid >> 6;
  const int c15 = lane & 15, kg = lane >> 4;
  const int n0 = blockIdx.x * 16;

  // stage w_route (8x1024 f32) via global_load_lds: 8 issues x 4 waves x 1KB
  #pragma unroll
  for (int q = 0; q < 8; ++q)
    load_lds16(w_route + (size_t)(q * 4 + wv) * 256 + lane * 4,
               wlds + (q * 4 + wv) * 256);

  // ---- ce partial over K-quarter [wv*256, wv*256+256)
  f32x4 acc = {0.f, 0.f, 0.f, 0.f};
  const float*     xrow = x    + (size_t)(n0 + c15) * 1024 + wv * 256 + kg * 8;
  const _Float16*  arow = Cf16 + (size_t)c15 * 1024        + wv * 256 + kg * 8;
  #pragma unroll
  for (int s = 0; s < 8; ++s){
    half8 a = *(const half8*)(arow + s * 32);
    float4 xa = *(const float4*)(xrow + s * 32);
    float4 xb = *(const float4*)(xrow + s * 32 + 4);
    half8 b;
    b[0]=(_Float16)xa.x; b[1]=(_Float16)xa.y; b[2]=(_Float16)xa.z; b[3]=(_Float16)xa.w;
    b[4]=(_Float16)xb.x; b[5]=(_Float16)xb.y; b[6]=(_Float16)xb.z; b[7]=(_Float16)xb.w;
    acc = __builtin_amdgcn_mfma_f32_16x16x32_f16(a, b, acc, 0, 0, 0);
  }
  ceacc[wv][lane] = acc;
  __syncthreads();   // covers w_route staging (vmcnt drain) + ceacc writes

  // ---- ce finalize: wave 0 sums the 4 K-quarters, stores f16
  if (wv == 0){
    f32x4 s0 = ceacc[0][lane], s1 = ceacc[1][lane];
    f32x4 s2 = ceacc[2][lane], s3 = ceacc[3][lane];
    f32x4 sm = (s0 + s1) + (s2 + s3);
    half4 h;
    h[0]=(_Float16)sm[0]; h[1]=(_Float16)sm[1]; h[2]=(_Float16)sm[2]; h[3]=(_Float16)sm[3];
    // D row = r = kg*4+v, col = token = c15
    *(half4*)(ce16 + (size_t)(n0 + c15) * 16 + kg * 4) = h;
  }

  // ---- router: wave handles 4 tokens as 2 sub-batches of 2
  const int b0 = lane & 1;
  #pragma unroll
  for (int sb = 0; sb < 2; ++sb){
    const int t0 = n0 + wv * 4 + sb * 2;
    float4 xv0[4], xv1[4];
    const float4* xr0 = (const float4*)(x + (size_t)t0 * 1024);
    const float4* xr1 = (const float4*)(x + (size_t)(t0 + 1) * 1024);
    #pragma unroll
    for (int c = 0; c < 4; ++c){ xv0[c] = xr0[c * 64 + lane]; xv1[c] = xr1[c * 64 + lane]; }
    float a0[8], a1[8];
    #pragma unroll
    for (int j = 0; j < 8; ++j){ a0[j] = 0.f; a1[j] = 0.f; }
    #pragma unroll
    for (int j = 0; j < 8; ++j)
      #pragma unroll
      for (int c = 0; c < 4; ++c){
        float4 w4 = *(const float4*)(wlds + j * 1024 + c * 256 + lane * 4);
        a0[j] += dot4f(xv0[c], w4);
        a1[j] += dot4f(xv1[c], w4);
      }
    // fold token onto lane bit0, butterfly bits 1-5
    float r[8];
    #pragma unroll
    for (int j = 0; j < 8; ++j){
      float p = b0 ? a1[j] : a0[j];
      float q = b0 ? a0[j] : a1[j];
      r[j] = p + __shfl_xor(q, 1, 64);
    }
    #pragma unroll
    for (int d = 2; d < 64; d <<= 1)
      #pragma unroll
      for (int j = 0; j < 8; ++j) r[j] += __shfl_xor(r[j], d, 64);
    // lane parity -> token t0 + (lane&1); top-2 (ties: lower index, matches jax)
    float v0 = r[0]; int e0 = 0;
    #pragma unroll
    for (int e = 1; e < 8; ++e) if (r[e] > v0){ v0 = r[e]; e0 = e; }
    float v1 = -3.402823466e38f; int e1 = 0;
    #pragma unroll
    for (int e = 0; e < 8; ++e) if (e != e0 && r[e] > v1){ v1 = r[e]; e1 = e; }
    float ex  = __expf(v1 - v0);
    float inv = 1.0f / (1.0f + ex);
    if (lane < 2 && t0 + lane < ntok)
      gate_ws[t0 + lane] = make_float4(__int_as_float(e0), __int_as_float(e1),
                                       inv, ex * inv);
  }
}

// ---------------- Kernel 2: out = (gate⊙ce) @ Bt^T, roles swapped so D rows = o.
// A = Bt (rows = o), B = gated-ce (cols = token) built on the fly per lane.
// Lane stores float4 (4 consecutive o) per nc-tile. XCD-swizzled grid.
__global__ __launch_bounds__(256) void k2_gemm(
    const _Float16* __restrict__ Bt, const _Float16* __restrict__ ce16,
    const float4* __restrict__ gate_ws, float* __restrict__ out, int ntok)
{
  const int g   = blockIdx.x;
  const int xcd = g & 7;
  const int j   = g >> 3;
  const int bn  = j & 15;
  const int bm  = xcd * (gridDim.x >> 7) + (j >> 4);   // 4096 blocks -> 32 bm/XCD
  const int lane = threadIdx.x & 63;
  const int wv   = threadIdx.x >> 6;
  const int n0   = bm * 64 + wv * 16;
  const int o0   = bn * 64;
  const int c15  = lane & 15;
  const int kg   = lane >> 4;

  // B-fragment (gated ce) for this lane's token, 4 k-steps
  const int tok = n0 + c15;
  half8 ce8 = *(const half8*)(ce16 + (size_t)tok * 16 + (kg & 1) * 8);
  float4 gt = gate_ws[tok];
  const int e0 = __float_as_int(gt.x), e1 = __float_as_int(gt.y);
  const int eb = kg >> 1;
  half8 bfr[4];
  #pragma unroll
  for (int s = 0; s < 4; ++s){
    const int e = 2 * s + eb;                 // expert of k-range [s*32+kg*8, +8)
    float sc = (e == e0) ? gt.z : ((e == e1) ? gt.w : 0.f);
    _Float16 sh = (_Float16)sc;
    #pragma unroll
    for (int q = 0; q < 8; ++q) bfr[s][q] = ce8[q] * sh;
  }

  f32x4 acc[4] = {{0.f,0.f,0.f,0.f},{0.f,0.f,0.f,0.f},{0.f,0.f,0.f,0.f},{0.f,0.f,0.f,0.f}};
  #pragma unroll
  for (int s = 0; s < 4; ++s){
    #pragma unroll
    for (int nc = 0; nc < 4; ++nc){
      half8 a = *(const half8*)(Bt + (size_t)(o0 + nc * 16 + c15) * 128 + s * 32 + kg * 8);
      acc[nc] = __builtin_amdgcn_mfma_f32_16x16x32_f16(a, bfr[s], acc[nc], 0, 0, 0);
    }
  }

  // D[row = o-local = kg*4+v][col = token = c15] -> one float4 store per nc
  #pragma unroll
  for (int nc = 0; nc < 4; ++nc){
    float4 o4 = make_float4(acc[nc][0], acc[nc][1], acc[nc][2], acc[nc][3]);
    *(float4*)(out + (size_t)tok * 1024 + o0 + nc * 16 + kg * 4) = o4;
  }
}

extern "C" void kernel_launch(void* const* d_in, const int* in_sizes, int n_in,
                              void* d_out, int out_size, void* d_ws, size_t ws_size,
                              hipStream_t stream)
{
  const float* x        = (const float*)d_in[0];
  const float* w_route  = (const float*)d_in[1];
  const float* compress = (const float*)d_in[2];
  const float* routed   = (const float*)d_in[3];
  float* out = (float*)d_out;

  const int ntok = in_sizes[0] / 1024;   // 16384 (B*T)
  char* ws = (char*)d_ws;
  _Float16* ce16    = (_Float16*)ws;                          // ntok*16 f16   (512 KB)
  float4*   gate_ws = (float4*)(ws + (size_t)ntok * 32);      // ntok float4   (256 KB)
  _Float16* Bt      = (_Float16*)(ws + (size_t)ntok * 48);    // 1024*128 f16  (256 KB)
  _Float16* Cf16    = (_Float16*)(ws + (size_t)ntok * 48 + 262144);  // 16*1024 f16 (32 KB)

  k0_prep<<<40, 256, 0, stream>>>(routed, compress, Bt, Cf16);
  k_main<<<ntok / 16, 256, 0, stream>>>(x, w_route, Cf16, ce16, gate_ws, ntok);
  k2_gemm<<<(ntok / 64) * 16, 256, 0, stream>>>(Bt, ce16, gate_ws, out, ntok);
}

// Round 5
// 48.123 us; speedup vs baseline: 2.9520x; 1.4505x over previous
//
#include <hip/hip_runtime.h>

// TMoELayer: B=4,T=4096 -> N=16384 tokens, D_IN=1024, D_OUT=1024, E=8, TOP_K=2, R=16
// out[n][o] = sum_k (gate(n,e)*ce16[n][r]) * Bt[o][k], k = e*16+r
// Router logits via split-precision MFMA: W = Whi + Wlo/1024 (f16 pair),
// X = Xhi + Xlo (f16 pair) -> logit = Whi.Xhi + Whi.Xlo + (Wlo.Xhi + Wlo.Xlo)/1024.
constexpr float SCALING = 2.0f;  // alpha/r = 32/16

typedef __attribute__((ext_vector_type(8))) _Float16 half8;
typedef __attribute__((ext_vector_type(4))) _Float16 half4;
typedef __attribute__((ext_vector_type(4))) float    f32x4;

// ---------------- Kernel 0: prep
//  Bt[o][k]   = (f16) routed[e][o][r]                (256 KB)
//  A2[r][d]   = (f16)(2*compress[r][d])              (32 KB, 16 rows)
//  A1[j][d]   = (f16) w_route[j][d]          j<8
//  A1[j+8][d] = (f16)((w_route[j][d]-hi)*1024)       (32 KB, 16 rows)
__global__ __launch_bounds__(256) void k0_prep(
    const float* __restrict__ routed, const float* __restrict__ compress,
    const float* __restrict__ w_route, _Float16* __restrict__ Bt,
    _Float16* __restrict__ A1, _Float16* __restrict__ A2)
{
  const int bid = blockIdx.x, tid = threadIdx.x;
  if (bid < 32){
    const int t = bid * 256 + tid;            // 0..8191
    const int e = t & 7, o = t >> 3;
    const float4* rp = (const float4*)(routed + ((size_t)e * 1024 + o) * 16);
    float4 a = rp[0], b = rp[1], c = rp[2], d = rp[3];
    half8 h0, h1;
    h0[0]=(_Float16)a.x; h0[1]=(_Float16)a.y; h0[2]=(_Float16)a.z; h0[3]=(_Float16)a.w;
    h0[4]=(_Float16)b.x; h0[5]=(_Float16)b.y; h0[6]=(_Float16)b.z; h0[7]=(_Float16)b.w;
    h1[0]=(_Float16)c.x; h1[1]=(_Float16)c.y; h1[2]=(_Float16)c.z; h1[3]=(_Float16)c.w;
    h1[4]=(_Float16)d.x; h1[5]=(_Float16)d.y; h1[6]=(_Float16)d.z; h1[7]=(_Float16)d.w;
    _Float16* dst = Bt + (size_t)o * 128 + e * 16;
    *(half8*)(dst)     = h0;
    *(half8*)(dst + 8) = h1;
  } else if (bid < 40){
    const int t2 = (bid - 32) * 256 + tid;    // 0..2047, 8 f32 each
    const float4* cp = (const float4*)(compress) + (size_t)t2 * 2;
    float4 a = cp[0], b = cp[1];
    half8 h;
    h[0]=(_Float16)(SCALING*a.x); h[1]=(_Float16)(SCALING*a.y);
    h[2]=(_Float16)(SCALING*a.z); h[3]=(_Float16)(SCALING*a.w);
    h[4]=(_Float16)(SCALING*b.x); h[5]=(_Float16)(SCALING*b.y);
    h[6]=(_Float16)(SCALING*b.z); h[7]=(_Float16)(SCALING*b.w);
    *(half8*)(A2 + (size_t)t2 * 8) = h;
  } else {
    const int t3 = (bid - 40) * 256 + tid;    // 0..2047, 4 f32 of w_route each
    const int j = t3 >> 8, d = (t3 & 255) * 4;
    float4 w = ((const float4*)w_route)[t3];
    half4 hi, lo;
    hi[0]=(_Float16)w.x; hi[1]=(_Float16)w.y; hi[2]=(_Float16)w.z; hi[3]=(_Float16)w.w;
    lo[0]=(_Float16)((w.x-(float)hi[0])*1024.f);
    lo[1]=(_Float16)((w.y-(float)hi[1])*1024.f);
    lo[2]=(_Float16)((w.z-(float)hi[2])*1024.f);
    lo[3]=(_Float16)((w.w-(float)hi[3])*1024.f);
    *(half4*)(A1 + (size_t)j * 1024 + d)       = hi;
    *(half4*)(A1 + (size_t)(j + 8) * 1024 + d) = lo;
  }
}

// ---------------- Kernel 1: all-MFMA router + ce. Block = 16 tokens, 4 waves
// (each wave one K-quarter of 256). Per step: 3 MFMAs (A1*Xhi, A1*Xlo, A2*Xhi).
// Partials reduced via 12KB LDS; wave 0 combines logits, top-2, softmax, stores.
__global__ __launch_bounds__(256, 4) void k_main(
    const float* __restrict__ x, const _Float16* __restrict__ A1,
    const _Float16* __restrict__ A2, _Float16* __restrict__ ce16,
    float4* __restrict__ gate_ws, int ntok)
{
  __shared__ f32x4 p1[4][64], p2[4][64], p3[4][64];   // 12 KB
  const int tid = threadIdx.x, lane = tid & 63, wv = tid >> 6;
  const int c15 = lane & 15, kg = lane >> 4;
  const int n0 = blockIdx.x * 16;

  const float*    xb  = x  + (size_t)(n0 + c15) * 1024 + wv * 256 + kg * 8;
  const _Float16* a1b = A1 + (size_t)c15 * 1024 + wv * 256 + kg * 8;
  const _Float16* a2b = A2 + (size_t)c15 * 1024 + wv * 256 + kg * 8;

  f32x4 acc1 = {0.f,0.f,0.f,0.f};   // [Whi;Wlo] * Xhi
  f32x4 acc3 = {0.f,0.f,0.f,0.f};   // [Whi;Wlo] * Xlo
  f32x4 acc2 = {0.f,0.f,0.f,0.f};   // (2*compress) * Xhi
  #pragma unroll
  for (int s = 0; s < 8; ++s){
    float4 xa = *(const float4*)(xb + s * 32);
    float4 xc = *(const float4*)(xb + s * 32 + 4);
    half8 a1 = *(const half8*)(a1b + s * 32);
    half8 a2 = *(const half8*)(a2b + s * 32);
    half8 bhi, blo;
    float xs[8] = {xa.x, xa.y, xa.z, xa.w, xc.x, xc.y, xc.z, xc.w};
    #pragma unroll
    for (int q = 0; q < 8; ++q){
      _Float16 h = (_Float16)xs[q];
      bhi[q] = h;
      blo[q] = (_Float16)(xs[q] - (float)h);
    }
    acc1 = __builtin_amdgcn_mfma_f32_16x16x32_f16(a1, bhi, acc1, 0, 0, 0);
    acc3 = __builtin_amdgcn_mfma_f32_16x16x32_f16(a1, blo, acc3, 0, 0, 0);
    acc2 = __builtin_amdgcn_mfma_f32_16x16x32_f16(a2, bhi, acc2, 0, 0, 0);
  }
  p1[wv][lane] = acc1;  p3[wv][lane] = acc3;  p2[wv][lane] = acc2;
  __syncthreads();
  if (wv != 0) return;

  f32x4 L = (p1[0][lane] + p1[1][lane]) + (p1[2][lane] + p1[3][lane]);
  f32x4 X = (p3[0][lane] + p3[1][lane]) + (p3[2][lane] + p3[3][lane]);
  f32x4 C = (p2[0][lane] + p2[1][lane]) + (p2[2][lane] + p2[3][lane]);

  // ce store: D2 row = r = kg*4+v, col = token = c15
  half4 hce;
  hce[0]=(_Float16)C[0]; hce[1]=(_Float16)C[1]; hce[2]=(_Float16)C[2]; hce[3]=(_Float16)C[3];
  *(half4*)(ce16 + (size_t)(n0 + c15) * 16 + kg * 4) = hce;

  // logits: rows 0..7 (lanes kg 0/1) get cross-lane Wlo terms from rows 8..15
  float lg[4];
  #pragma unroll
  for (int v = 0; v < 4; ++v){
    float wlo_xhi = __shfl_xor(L[v], 32, 64);
    float wlo_xlo = __shfl_xor(X[v], 32, 64);
    lg[v] = L[v] + X[v] + (wlo_xhi + wlo_xlo) * (1.0f / 1024.0f);
  }
  // gather e4..7 from lane+16
  float l8[8];
  #pragma unroll
  for (int v = 0; v < 4; ++v){
    l8[v]     = lg[v];
    l8[4 + v] = __shfl_xor(lg[v], 16, 64);
  }
  if (lane < 16 && n0 + lane < ntok){
    float v0 = l8[0]; int e0 = 0;
    #pragma unroll
    for (int e = 1; e < 8; ++e) if (l8[e] > v0){ v0 = l8[e]; e0 = e; }
    float v1 = -3.402823466e38f; int e1 = 0;
    #pragma unroll
    for (int e = 0; e < 8; ++e) if (e != e0 && l8[e] > v1){ v1 = l8[e]; e1 = e; }
    float ex  = __expf(v1 - v0);
    float inv = 1.0f / (1.0f + ex);
    gate_ws[n0 + lane] = make_float4(__int_as_float(e0), __int_as_float(e1),
                                     inv, ex * inv);
  }
}

// ---------------- Kernel 2: out = (gate⊙ce) @ Bt^T.
// grid 1024 (4 blocks/CU). Block = 16 tokens x 256 o per iter, 4 iters.
// Bt fragments register-resident across iters; ce/gate prefetched one iter ahead.
// acc -> padded LDS -> one contiguous 1KB store per wave-instruction.
__global__ __launch_bounds__(256, 4) void k2_gemm(
    const _Float16* __restrict__ Bt, const _Float16* __restrict__ ce16,
    const float4* __restrict__ gate_ws, float* __restrict__ out, int ntok)
{
  __shared__ float lds[16][260];   // +4 pad: bank-conflict-free b128 write/read
  const int tid = threadIdx.x, lane = tid & 63, wv = tid >> 6;
  const int c15 = lane & 15, kg = lane >> 4;
  const int bn = blockIdx.x & 3;          // o-chunk of 256
  const int tg = blockIdx.x >> 2;         // token group of 64
  const int o0w = bn * 256 + wv * 64;

  // Bt fragments for this wave's 64 o x 128 k: 16 x half8 (64 VGPR), reused 4x
  half8 bt[4][4];
  #pragma unroll
  for (int nc = 0; nc < 4; ++nc)
    #pragma unroll
    for (int s = 0; s < 4; ++s)
      bt[nc][s] = *(const half8*)(Bt + (size_t)(o0w + nc * 16 + c15) * 128
                                  + s * 32 + kg * 8);

  int tok = tg * 64 + c15;
  half8  ce_n = *(const half8*)(ce16 + (size_t)tok * 16 + (kg & 1) * 8);
  float4 gt_n = gate_ws[tok];

  #pragma unroll
  for (int i = 0; i < 4; ++i){
    half8 ce_c = ce_n;  float4 gt_c = gt_n;
    if (i < 3){
      const int tok2 = tg * 64 + (i + 1) * 16 + c15;
      ce_n = *(const half8*)(ce16 + (size_t)tok2 * 16 + (kg & 1) * 8);
      gt_n = gate_ws[tok2];
    }
    const int e0 = __float_as_int(gt_c.x), e1 = __float_as_int(gt_c.y);
    const int eb = kg >> 1;

    f32x4 acc[4] = {{0.f,0.f,0.f,0.f},{0.f,0.f,0.f,0.f},
                    {0.f,0.f,0.f,0.f},{0.f,0.f,0.f,0.f}};
    #pragma unroll
    for (int s = 0; s < 4; ++s){
      const int e = 2 * s + eb;           // expert of k-range [s*32+kg*8, +8)
      float sc = (e == e0) ? gt_c.z : ((e == e1) ? gt_c.w : 0.f);
      _Float16 sh = (_Float16)sc;
      half8 bfr;
      #pragma unroll
      for (int q = 0; q < 8; ++q) bfr[q] = ce_c[q] * sh;
      #pragma unroll
      for (int nc = 0; nc < 4; ++nc)
        acc[nc] = __builtin_amdgcn_mfma_f32_16x16x32_f16(bt[nc][s], bfr, acc[nc], 0, 0, 0);
    }
    // D[row = o-local = kg*4+v][col = token = c15] -> LDS[token][o-local]
    #pragma unroll
    for (int nc = 0; nc < 4; ++nc)
      *(float4*)&lds[c15][wv * 64 + nc * 16 + kg * 4] =
          make_float4(acc[nc][0], acc[nc][1], acc[nc][2], acc[nc][3]);
    __syncthreads();

    // coalesced store: wave w writes rows {w, w+4, w+8, w+12}, 1KB contiguous each
    const int n0i = tg * 64 + i * 16;
    #pragma unroll
    for (int p = 0; p < 4; ++p){
      const int row = p * 4 + wv;
      const int col = lane * 4;
      float4 v = *(const float4*)&lds[row][col];
      *(float4*)(out + (size_t)(n0i + row) * 1024 + bn * 256 + col) = v;
    }
    if (i < 3) __syncthreads();
  }
}

extern "C" void kernel_launch(void* const* d_in, const int* in_sizes, int n_in,
                              void* d_out, int out_size, void* d_ws, size_t ws_size,
                              hipStream_t stream)
{
  const float* x        = (const float*)d_in[0];
  const float* w_route  = (const float*)d_in[1];
  const float* compress = (const float*)d_in[2];
  const float* routed   = (const float*)d_in[3];
  float* out = (float*)d_out;

  const int ntok = in_sizes[0] / 1024;   // 16384 (B*T)
  char* ws = (char*)d_ws;
  _Float16* ce16    = (_Float16*)ws;                               // ntok*16 f16  (512 KB)
  float4*   gate_ws = (float4*)(ws + (size_t)ntok * 32);           // ntok*16 B    (256 KB)
  _Float16* Bt      = (_Float16*)(ws + (size_t)ntok * 48);         // 1024*128 f16 (256 KB)
  _Float16* A1      = (_Float16*)(ws + (size_t)ntok * 48 + 262144);          // 32 KB
  _Float16* A2      = (_Float16*)(ws + (size_t)ntok * 48 + 262144 + 32768);  // 32 KB

  k0_prep<<<48, 256, 0, stream>>>(routed, compress, w_route, Bt, A1, A2);
  k_main<<<ntok / 16, 256, 0, stream>>>(x, A1, A2, ce16, gate_ws, ntok);
  k2_gemm<<<(ntok / 64) * 4, 256, 0, stream>>>(Bt, ce16, gate_ws, out, ntok);
}